// Round 16
// baseline (150.524 us; speedup 1.0000x reference)
//
#include <hip/hip_runtime.h>
#include <hip/hip_fp16.h>

#define NN 100000
#define NE 1600000
#define IN_DIM 32
#define HID_DIM 16
#define OUT_DIM 8

#define NPB 128                       // nodes per bucket (power of 2)
#define NBK ((NN + NPB - 1) / NPB)    // 782 buckets
#define CAP 3200                      // bucket capacity (mean 2048, ~25 sigma)
#define EPB 4096                      // edges per bucket-task
#define BS1 512                       // phase1 block size (8 waves for latency hiding)
#define EPT (EPB / BS1)               // 8 edges per thread
#define NT_BUCKET ((NE + EPB - 1) / EPB)   // 391
#define NT_PRE1 ((NN + BS1 - 1) / BS1)     // 196
#define GRID1 (NT_BUCKET + NT_PRE1)        // 587
#define BF_STRIDE 16                  // bucketfill: 1 counter per 64B line
#define SCAN_CHUNKS ((NBK + BS1 - 1) / BS1)  // 2

// =============== kernel 1 (512 thr): bucket edges (sorted-in-LDS) || pre1 ===============
__global__ __launch_bounds__(BS1) void k_phase1(
    const float* __restrict__ x, const int* __restrict__ src, const int* __restrict__ dst,
    const float* __restrict__ Wl1, const float* __restrict__ bl1, const float* __restrict__ Wr1,
    const float* __restrict__ Wl2, const float* __restrict__ bl2, const float* __restrict__ Wr2,
    const float* __restrict__ Wfc, const float* __restrict__ bfc,
    int* __restrict__ bucketfill, unsigned int* __restrict__ bucket,
    __half* __restrict__ zh, float* __restrict__ rb, float* __restrict__ uvc)
{
    __shared__ int lcnt[NBK];
    __shared__ int lpos[NBK];
    __shared__ int lbase[NBK];
    __shared__ int lfill[NBK];
    __shared__ int swsum[8];
    __shared__ unsigned int ssorted[EPB];        // 16 KB
    __shared__ unsigned short sbin[EPB];         // 8 KB
    int tid = threadIdx.x;

    if (blockIdx.x < NT_BUCKET) {
        int e0 = blockIdx.x * EPB;
        int e1 = min(e0 + EPB, NE);
        int total = e1 - e0;
        int lane = tid & 63;
        int w = tid >> 6;              // 0..7

        for (int i = tid; i < NBK; i += BS1) lcnt[i] = 0;
        __syncthreads();

        // 1. load dst into registers + count bins
        int myd[EPT];
#pragma unroll
        for (int k = 0; k < EPT; k++) {
            int e = e0 + k * BS1 + tid;
            myd[k] = (e < e1) ? dst[e] : -1;
            if (myd[k] >= 0) atomicAdd(&lcnt[myd[k] >> 7], 1);
        }
        __syncthreads();

        // 2. scan NBK bins: wave-shuffle scan per 512-chunk, carry across chunks
        int carry = 0;
        for (int ch = 0; ch < SCAN_CHUNKS; ch++) {
            int idx = ch * BS1 + tid;
            int v = (idx < NBK) ? lcnt[idx] : 0;
            int incl = v;
#pragma unroll
            for (int off = 1; off < 64; off <<= 1) {
                int t = __shfl_up(incl, off);
                if (lane >= off) incl += t;
            }
            if (lane == 63) swsum[w] = incl;
            __syncthreads();
            int pre = carry;
            for (int ww = 0; ww < w; ww++) pre += swsum[ww];
            if (idx < NBK) lpos[idx] = pre + incl - v;
            carry += swsum[0] + swsum[1] + swsum[2] + swsum[3]
                   + swsum[4] + swsum[5] + swsum[6] + swsum[7];
            __syncthreads();
        }

        // 3. claim global runs + init scatter cursors
        for (int i = tid; i < NBK; i += BS1) {
            lbase[i] = (lcnt[i] > 0) ? atomicAdd(&bucketfill[i * BF_STRIDE], lcnt[i]) : 0;
            lfill[i] = lpos[i];
        }
        __syncthreads();

        // 4. scatter into sorted LDS buffer
#pragma unroll
        for (int k = 0; k < EPT; k++) {
            if (myd[k] >= 0) {
                int e = e0 + k * BS1 + tid;
                int s = src[e];
                int b = myd[k] >> 7;
                int p = atomicAdd(&lfill[b], 1);
                ssorted[p] = (unsigned)(myd[k] & (NPB - 1)) | ((unsigned)s << 7);
                sbin[p] = (unsigned short)b;
            }
        }
        __syncthreads();

        // 5. coalesced write-out
        for (int i = tid; i < total; i += BS1) {
            int b = sbin[i];
            bucket[(size_t)b * CAP + lbase[b] + (i - lpos[b])] = ssorted[i];
        }
    } else {
        int chunk = blockIdx.x - NT_BUCKET;
        float* sWl = (float*)ssorted;        // 512 floats
        float* sWr = sWl + 512;              // 512 floats (still within 16 KB)
        float* sb  = (float*)sbin;           // 16 floats
        for (int i = tid; i < HID_DIM * IN_DIM; i += BS1) {
            sWl[i] = Wl1[i];
            sWr[i] = Wr1[i];
        }
        if (tid < HID_DIM) sb[tid] = bl1[tid];
        if (chunk == 0) {
            if (tid < HID_DIM) {
                float uu = 0.f, vv = 0.f;
#pragma unroll
                for (int o = 0; o < OUT_DIM; o++) {
                    uu += Wfc[o] * Wl2[o * HID_DIM + tid];
                    vv += Wfc[o] * Wr2[o * HID_DIM + tid];
                }
                uvc[tid] = uu;
                uvc[HID_DIM + tid] = vv;
            }
            if (tid == 0) {
                float c0 = bfc[0];
#pragma unroll
                for (int o = 0; o < OUT_DIM; o++) c0 += Wfc[o] * bl2[o];
                uvc[2 * HID_DIM] = c0;
            }
        }
        __syncthreads();
        int n = chunk * BS1 + tid;
        if (n < NN) {
            float xv[IN_DIM];
            const float4* x4 = (const float4*)(x + (size_t)n * IN_DIM);
#pragma unroll
            for (int c = 0; c < 8; c++) {
                float4 b = x4[c];
                xv[c * 4 + 0] = b.x; xv[c * 4 + 1] = b.y;
                xv[c * 4 + 2] = b.z; xv[c * 4 + 3] = b.w;
            }
            float zo[HID_DIM], ro[HID_DIM];
#pragma unroll
            for (int o = 0; o < HID_DIM; o++) {
                float az = 0.f, ar = sb[o];
#pragma unroll
                for (int i = 0; i < IN_DIM; i++) {
                    az += sWl[o * IN_DIM + i] * xv[i];
                    ar += sWr[o * IN_DIM + i] * xv[i];
                }
                zo[o] = az; ro[o] = ar;
            }
            // z stored as fp16 (row = 16 halves = 32 B)
            __half2 hh[8];
#pragma unroll
            for (int c = 0; c < 8; c++) hh[c] = __floats2half2_rn(zo[2 * c], zo[2 * c + 1]);
            float4* zh4 = (float4*)(zh + (size_t)n * HID_DIM);
            zh4[0] = *(float4*)&hh[0];
            zh4[1] = *(float4*)&hh[4];
            float4* r4 = (float4*)(rb + (size_t)n * HID_DIM);
#pragma unroll
            for (int c = 0; c < 4; c++) {
                r4[c] = make_float4(ro[c*4], ro[c*4+1], ro[c*4+2], ro[c*4+3]);
            }
        }
    }
}

// =============== kernel 2: per-bucket LDS sort + fused gather_h (z fp16, bucket staged) ===============
__global__ __launch_bounds__(256) void k_sort_gather(
    const int* __restrict__ bucketfill, const unsigned int* __restrict__ bucket,
    const __half* __restrict__ zh, const float* __restrict__ rb, const float* __restrict__ uvc,
    int* __restrict__ deg, float* __restrict__ sv, float* __restrict__ tv)
{
    __shared__ int lcnt[NPB];
    __shared__ int lscan[NPB];
    __shared__ int lfill[NPB];
    __shared__ int wsum0;
    __shared__ unsigned int sbk[CAP];    // staged bucket words (12.8 KB)
    __shared__ int ssrc[CAP];            // sorted src ids (12.8 KB)

    int b = blockIdx.x;
    int tid = threadIdx.x;
    int cntb = bucketfill[b * BF_STRIDE];
    const unsigned int* bk = bucket + (size_t)b * CAP;

    if (tid < NPB) lcnt[tid] = 0;
    for (int i = tid; i < cntb; i += 256) sbk[i] = bk[i];
    __syncthreads();
    for (int i = tid; i < cntb; i += 256) atomicAdd(&lcnt[sbk[i] & (NPB - 1)], 1);
    __syncthreads();

    // wave-shuffle scan over 128 bins (waves 0,1)
    {
        int lane = tid & 63;
        int v = (tid < NPB) ? lcnt[tid] : 0;
        int incl = v;
#pragma unroll
        for (int off = 1; off < 64; off <<= 1) {
            int t = __shfl_up(incl, off);
            if (lane >= off) incl += t;
        }
        if (tid == 63) wsum0 = incl;
        __syncthreads();
        if (tid >= 64 && tid < NPB) incl += wsum0;
        if (tid < NPB) {
            lscan[tid] = incl;
            lfill[tid] = incl - v;
            int node = b * NPB + tid;
            if (node < NN) deg[node] = v;
        }
    }
    __syncthreads();
    for (int i = tid; i < cntb; i += 256) {
        unsigned v = sbk[i];
        int d = v & (NPB - 1);
        int p = atomicAdd(&lfill[d], 1);
        ssrc[p] = (int)(v >> 7);
    }
    __syncthreads();

    // fused gather_h: 2 passes x (64 nodes x 4 lanes); z row = 4 float2 (fp16x4 each)
    int c = tid & 3;
    int nl0 = tid >> 2;
    float4 u4 = ((const float4*)uvc)[c];
    float4 v4 = ((const float4*)uvc)[4 + c];
    const float2* z2p = (const float2*)zh;   // one float2 = 4 halves
#pragma unroll
    for (int pass = 0; pass < 2; pass++) {
        int nl = pass * 64 + nl0;
        int n2 = b * NPB + nl;
        if (n2 < NN) {
            int dg = lcnt[nl];
            int st = lscan[nl] - dg;
            float4 acc = {0.f, 0.f, 0.f, 0.f};
            int i = 0;
            for (; i + 4 <= dg; i += 4) {
                int s0 = ssrc[st + i + 0];
                int s1 = ssrc[st + i + 1];
                int s2 = ssrc[st + i + 2];
                int s3 = ssrc[st + i + 3];
                float2 w0 = z2p[s0 * 4 + c];
                float2 w1 = z2p[s1 * 4 + c];
                float2 w2 = z2p[s2 * 4 + c];
                float2 w3 = z2p[s3 * 4 + c];
                float2 a0 = __half22float2(*(__half2*)&w0.x), b0 = __half22float2(*(__half2*)&w0.y);
                float2 a1 = __half22float2(*(__half2*)&w1.x), b1 = __half22float2(*(__half2*)&w1.y);
                float2 a2 = __half22float2(*(__half2*)&w2.x), b2 = __half22float2(*(__half2*)&w2.y);
                float2 a3 = __half22float2(*(__half2*)&w3.x), b3 = __half22float2(*(__half2*)&w3.y);
                acc.x += a0.x + a1.x + a2.x + a3.x;
                acc.y += a0.y + a1.y + a2.y + a3.y;
                acc.z += b0.x + b1.x + b2.x + b3.x;
                acc.w += b0.y + b1.y + b2.y + b3.y;
            }
            for (; i < dg; i++) {
                float2 w = z2p[ssrc[st + i] * 4 + c];
                float2 a = __half22float2(*(__half2*)&w.x), bb = __half22float2(*(__half2*)&w.y);
                acc.x += a.x; acc.y += a.y; acc.z += bb.x; acc.w += bb.y;
            }
            float inv = 1.0f / fmaxf((float)dg, 1.0f);
            float4 r = ((const float4*)rb)[n2 * 4 + c];
            float h0 = fmaxf(acc.x * inv + r.x, 0.f);
            float h1 = fmaxf(acc.y * inv + r.y, 0.f);
            float h2 = fmaxf(acc.z * inv + r.z, 0.f);
            float h3 = fmaxf(acc.w * inv + r.w, 0.f);
            float ps = u4.x * h0 + u4.y * h1 + u4.z * h2 + u4.w * h3;
            float pt = v4.x * h0 + v4.y * h1 + v4.z * h2 + v4.w * h3;
            ps += __shfl_xor(ps, 1);
            ps += __shfl_xor(ps, 2);
            pt += __shfl_xor(pt, 1);
            pt += __shfl_xor(pt, 2);
            if (c == 0) { sv[n2] = ps; tv[n2] = pt; }
        }
    }
}

// =============== kernel 3: edge-centric out = mean(sv[src]) + tv + c0 ===============
__global__ __launch_bounds__(256) void k_final(
    const int* __restrict__ bucketfill, const unsigned int* __restrict__ bucket,
    const int* __restrict__ deg, const float* __restrict__ sv, const float* __restrict__ tv,
    const float* __restrict__ uvc, float* __restrict__ out)
{
    __shared__ float lsum[NPB];
    int b = blockIdx.x;
    int tid = threadIdx.x;
    int cntb = bucketfill[b * BF_STRIDE];
    const unsigned int* bk = bucket + (size_t)b * CAP;

    if (tid < NPB) lsum[tid] = 0.f;
    __syncthreads();
    for (int i = tid; i < cntb; i += 256) {
        unsigned v = bk[i];
        int d = v & (NPB - 1);
        int s = (int)(v >> 7);
        atomicAdd(&lsum[d], sv[s]);
    }
    __syncthreads();
    if (tid < NPB) {
        int n = b * NPB + tid;
        if (n < NN) {
            float dg = (float)deg[n];
            out[n] = lsum[tid] / fmaxf(dg, 1.0f) + tv[n] + uvc[2 * HID_DIM];
        }
    }
}

extern "C" void kernel_launch(void* const* d_in, const int* in_sizes, int n_in,
                              void* d_out, int out_size, void* d_ws, size_t ws_size,
                              hipStream_t stream) {
    const float* x   = (const float*)d_in[0];
    const int*   ei  = (const int*)d_in[1];
    const float* Wl1 = (const float*)d_in[2];
    const float* bl1 = (const float*)d_in[3];
    const float* Wr1 = (const float*)d_in[4];
    const float* Wl2 = (const float*)d_in[5];
    const float* bl2 = (const float*)d_in[6];
    const float* Wr2 = (const float*)d_in[7];
    const float* Wfc = (const float*)d_in[8];
    const float* bfc = (const float*)d_in[9];
    float* out = (float*)d_out;

    const int* src = ei;
    const int* dst = ei + NE;

    // ws layout:
    int* bucketfill = (int*)d_ws;                        // NBK*BF_STRIDE = 12512 -> pad 12544
    int* deg        = bucketfill + 12544;                // NN
    float* uvc      = (float*)(deg + NN);                // 40
    float* sv       = uvc + 40;                          // NN
    float* tv       = sv + NN;                           // NN
    unsigned int* bucket = (unsigned int*)(tv + NN);     // NBK*CAP (10 MB)
    __half* zh      = (__half*)(bucket + (size_t)NBK * CAP);   // NN*16 halves (3.2 MB)
    float* rb       = (float*)(zh + (size_t)NN * HID_DIM);     // NN*16 floats

    hipMemsetAsync(bucketfill, 0, NBK * BF_STRIDE * sizeof(int), stream);

    k_phase1<<<GRID1, BS1, 0, stream>>>(x, src, dst, Wl1, bl1, Wr1,
                                        Wl2, bl2, Wr2, Wfc, bfc,
                                        bucketfill, bucket, zh, rb, uvc);
    k_sort_gather<<<NBK, 256, 0, stream>>>(bucketfill, bucket, zh, rb, uvc, deg, sv, tv);
    k_final<<<NBK, 256, 0, stream>>>(bucketfill, bucket, deg, sv, tv, uvc, out);
}

// Round 17
// 135.369 us; speedup vs baseline: 1.1120x; 1.1120x over previous
//
#include <hip/hip_runtime.h>
#include <hip/hip_fp16.h>

#define NN 100000
#define NE 1600000
#define IN_DIM 32
#define HID_DIM 16
#define OUT_DIM 8

#define NPB 128                       // nodes per bucket (power of 2)
#define NBK ((NN + NPB - 1) / NPB)    // 782 buckets
#define CAP 3200                      // bucket capacity (mean 2048, ~25 sigma)
#define EPB 8192                      // edges per bucket-task (longer runs -> less write amp)
#define BS1 512                       // phase1 block size
#define EPT (EPB / BS1)               // 16 edges per thread (proven footprint)
#define NT_BUCKET ((NE + EPB - 1) / EPB)   // 196
#define NT_PRE1 ((NN + BS1 - 1) / BS1)     // 196
#define GRID1 (NT_BUCKET + NT_PRE1)        // 392
#define BF_STRIDE 16                  // bucketfill: 1 counter per 64B line
#define SCAN_CHUNKS ((NBK + BS1 - 1) / BS1)  // 2

// =============== kernel 1 (512 thr): bucket edges (sorted-in-LDS) || pre1 ===============
__global__ __launch_bounds__(BS1) void k_phase1(
    const float* __restrict__ x, const int* __restrict__ src, const int* __restrict__ dst,
    const float* __restrict__ Wl1, const float* __restrict__ bl1, const float* __restrict__ Wr1,
    const float* __restrict__ Wl2, const float* __restrict__ bl2, const float* __restrict__ Wr2,
    const float* __restrict__ Wfc, const float* __restrict__ bfc,
    int* __restrict__ bucketfill, unsigned int* __restrict__ bucket,
    __half* __restrict__ zh, float* __restrict__ rb, float* __restrict__ uvc)
{
    __shared__ int lcnt[NBK];
    __shared__ int lpos[NBK];
    __shared__ int lbase[NBK];
    __shared__ int lfill[NBK];
    __shared__ int swsum[8];
    __shared__ unsigned int ssorted[EPB];        // 32 KB
    __shared__ unsigned short sbin[EPB];         // 16 KB
    int tid = threadIdx.x;

    if (blockIdx.x < NT_BUCKET) {
        int e0 = blockIdx.x * EPB;
        int e1 = min(e0 + EPB, NE);
        int total = e1 - e0;
        int lane = tid & 63;
        int w = tid >> 6;              // 0..7

        for (int i = tid; i < NBK; i += BS1) lcnt[i] = 0;
        __syncthreads();

        // 1. load dst into registers + count bins
        int myd[EPT];
#pragma unroll
        for (int k = 0; k < EPT; k++) {
            int e = e0 + k * BS1 + tid;
            myd[k] = (e < e1) ? dst[e] : -1;
            if (myd[k] >= 0) atomicAdd(&lcnt[myd[k] >> 7], 1);
        }
        __syncthreads();

        // 2. scan NBK bins: wave-shuffle scan per 512-chunk, carry across chunks
        int carry = 0;
        for (int ch = 0; ch < SCAN_CHUNKS; ch++) {
            int idx = ch * BS1 + tid;
            int v = (idx < NBK) ? lcnt[idx] : 0;
            int incl = v;
#pragma unroll
            for (int off = 1; off < 64; off <<= 1) {
                int t = __shfl_up(incl, off);
                if (lane >= off) incl += t;
            }
            if (lane == 63) swsum[w] = incl;
            __syncthreads();
            int pre = carry;
            for (int ww = 0; ww < w; ww++) pre += swsum[ww];
            if (idx < NBK) lpos[idx] = pre + incl - v;
            carry += swsum[0] + swsum[1] + swsum[2] + swsum[3]
                   + swsum[4] + swsum[5] + swsum[6] + swsum[7];
            __syncthreads();
        }

        // 3. claim global runs + init scatter cursors
        for (int i = tid; i < NBK; i += BS1) {
            lbase[i] = (lcnt[i] > 0) ? atomicAdd(&bucketfill[i * BF_STRIDE], lcnt[i]) : 0;
            lfill[i] = lpos[i];
        }
        __syncthreads();

        // 4. scatter into sorted LDS buffer
#pragma unroll
        for (int k = 0; k < EPT; k++) {
            if (myd[k] >= 0) {
                int e = e0 + k * BS1 + tid;
                int s = src[e];
                int b = myd[k] >> 7;
                int p = atomicAdd(&lfill[b], 1);
                ssorted[p] = (unsigned)(myd[k] & (NPB - 1)) | ((unsigned)s << 7);
                sbin[p] = (unsigned short)b;
            }
        }
        __syncthreads();

        // 5. coalesced write-out
        for (int i = tid; i < total; i += BS1) {
            int b = sbin[i];
            bucket[(size_t)b * CAP + lbase[b] + (i - lpos[b])] = ssorted[i];
        }
    } else {
        int chunk = blockIdx.x - NT_BUCKET;
        float* sWl = (float*)ssorted;        // 512 floats
        float* sWr = sWl + 512;              // 512 floats
        float* sb  = (float*)sbin;           // 16 floats
        for (int i = tid; i < HID_DIM * IN_DIM; i += BS1) {
            sWl[i] = Wl1[i];
            sWr[i] = Wr1[i];
        }
        if (tid < HID_DIM) sb[tid] = bl1[tid];
        if (chunk == 0) {
            if (tid < HID_DIM) {
                float uu = 0.f, vv = 0.f;
#pragma unroll
                for (int o = 0; o < OUT_DIM; o++) {
                    uu += Wfc[o] * Wl2[o * HID_DIM + tid];
                    vv += Wfc[o] * Wr2[o * HID_DIM + tid];
                }
                uvc[tid] = uu;
                uvc[HID_DIM + tid] = vv;
            }
            if (tid == 0) {
                float c0 = bfc[0];
#pragma unroll
                for (int o = 0; o < OUT_DIM; o++) c0 += Wfc[o] * bl2[o];
                uvc[2 * HID_DIM] = c0;
            }
        }
        __syncthreads();
        int n = chunk * BS1 + tid;
        if (n < NN) {
            float xv[IN_DIM];
            const float4* x4 = (const float4*)(x + (size_t)n * IN_DIM);
#pragma unroll
            for (int c = 0; c < 8; c++) {
                float4 b = x4[c];
                xv[c * 4 + 0] = b.x; xv[c * 4 + 1] = b.y;
                xv[c * 4 + 2] = b.z; xv[c * 4 + 3] = b.w;
            }
            float zo[HID_DIM], ro[HID_DIM];
#pragma unroll
            for (int o = 0; o < HID_DIM; o++) {
                float az = 0.f, ar = sb[o];
#pragma unroll
                for (int i = 0; i < IN_DIM; i++) {
                    az += sWl[o * IN_DIM + i] * xv[i];
                    ar += sWr[o * IN_DIM + i] * xv[i];
                }
                zo[o] = az; ro[o] = ar;
            }
            // z stored as fp16 (row = 16 halves = 32 B)
            __half2 hh[8];
#pragma unroll
            for (int c = 0; c < 8; c++) hh[c] = __floats2half2_rn(zo[2 * c], zo[2 * c + 1]);
            float4* zh4 = (float4*)(zh + (size_t)n * HID_DIM);
            zh4[0] = *(float4*)&hh[0];
            zh4[1] = *(float4*)&hh[4];
            float4* r4 = (float4*)(rb + (size_t)n * HID_DIM);
#pragma unroll
            for (int c = 0; c < 4; c++) {
                r4[c] = make_float4(ro[c*4], ro[c*4+1], ro[c*4+2], ro[c*4+3]);
            }
        }
    }
}

// =============== kernel 2: per-bucket LDS sort + fused gather_h (z fp16, bucket staged) ===============
__global__ __launch_bounds__(256) void k_sort_gather(
    const int* __restrict__ bucketfill, const unsigned int* __restrict__ bucket,
    const __half* __restrict__ zh, const float* __restrict__ rb, const float* __restrict__ uvc,
    int* __restrict__ deg, float* __restrict__ sv, float* __restrict__ tv)
{
    __shared__ int lcnt[NPB];
    __shared__ int lscan[NPB];
    __shared__ int lfill[NPB];
    __shared__ int wsum0;
    __shared__ unsigned int sbk[CAP];    // staged bucket words (12.8 KB)
    __shared__ int ssrc[CAP];            // sorted src ids (12.8 KB)

    int b = blockIdx.x;
    int tid = threadIdx.x;
    int cntb = bucketfill[b * BF_STRIDE];
    const unsigned int* bk = bucket + (size_t)b * CAP;

    if (tid < NPB) lcnt[tid] = 0;
    for (int i = tid; i < cntb; i += 256) sbk[i] = bk[i];
    __syncthreads();
    for (int i = tid; i < cntb; i += 256) atomicAdd(&lcnt[sbk[i] & (NPB - 1)], 1);
    __syncthreads();

    // wave-shuffle scan over 128 bins (waves 0,1)
    {
        int lane = tid & 63;
        int v = (tid < NPB) ? lcnt[tid] : 0;
        int incl = v;
#pragma unroll
        for (int off = 1; off < 64; off <<= 1) {
            int t = __shfl_up(incl, off);
            if (lane >= off) incl += t;
        }
        if (tid == 63) wsum0 = incl;
        __syncthreads();
        if (tid >= 64 && tid < NPB) incl += wsum0;
        if (tid < NPB) {
            lscan[tid] = incl;
            lfill[tid] = incl - v;
            int node = b * NPB + tid;
            if (node < NN) deg[node] = v;
        }
    }
    __syncthreads();
    for (int i = tid; i < cntb; i += 256) {
        unsigned v = sbk[i];
        int d = v & (NPB - 1);
        int p = atomicAdd(&lfill[d], 1);
        ssrc[p] = (int)(v >> 7);
    }
    __syncthreads();

    // fused gather_h: 2 passes x (64 nodes x 4 lanes); z row = 4 float2 (fp16x4 each)
    int c = tid & 3;
    int nl0 = tid >> 2;
    float4 u4 = ((const float4*)uvc)[c];
    float4 v4 = ((const float4*)uvc)[4 + c];
    const float2* z2p = (const float2*)zh;   // one float2 = 4 halves
#pragma unroll
    for (int pass = 0; pass < 2; pass++) {
        int nl = pass * 64 + nl0;
        int n2 = b * NPB + nl;
        if (n2 < NN) {
            int dg = lcnt[nl];
            int st = lscan[nl] - dg;
            float4 acc = {0.f, 0.f, 0.f, 0.f};
            int i = 0;
            for (; i + 4 <= dg; i += 4) {
                int s0 = ssrc[st + i + 0];
                int s1 = ssrc[st + i + 1];
                int s2 = ssrc[st + i + 2];
                int s3 = ssrc[st + i + 3];
                float2 w0 = z2p[s0 * 4 + c];
                float2 w1 = z2p[s1 * 4 + c];
                float2 w2 = z2p[s2 * 4 + c];
                float2 w3 = z2p[s3 * 4 + c];
                float2 a0 = __half22float2(*(__half2*)&w0.x), b0 = __half22float2(*(__half2*)&w0.y);
                float2 a1 = __half22float2(*(__half2*)&w1.x), b1 = __half22float2(*(__half2*)&w1.y);
                float2 a2 = __half22float2(*(__half2*)&w2.x), b2 = __half22float2(*(__half2*)&w2.y);
                float2 a3 = __half22float2(*(__half2*)&w3.x), b3 = __half22float2(*(__half2*)&w3.y);
                acc.x += a0.x + a1.x + a2.x + a3.x;
                acc.y += a0.y + a1.y + a2.y + a3.y;
                acc.z += b0.x + b1.x + b2.x + b3.x;
                acc.w += b0.y + b1.y + b2.y + b3.y;
            }
            for (; i < dg; i++) {
                float2 w = z2p[ssrc[st + i] * 4 + c];
                float2 a = __half22float2(*(__half2*)&w.x), bb = __half22float2(*(__half2*)&w.y);
                acc.x += a.x; acc.y += a.y; acc.z += bb.x; acc.w += bb.y;
            }
            float inv = 1.0f / fmaxf((float)dg, 1.0f);
            float4 r = ((const float4*)rb)[n2 * 4 + c];
            float h0 = fmaxf(acc.x * inv + r.x, 0.f);
            float h1 = fmaxf(acc.y * inv + r.y, 0.f);
            float h2 = fmaxf(acc.z * inv + r.z, 0.f);
            float h3 = fmaxf(acc.w * inv + r.w, 0.f);
            float ps = u4.x * h0 + u4.y * h1 + u4.z * h2 + u4.w * h3;
            float pt = v4.x * h0 + v4.y * h1 + v4.z * h2 + v4.w * h3;
            ps += __shfl_xor(ps, 1);
            ps += __shfl_xor(ps, 2);
            pt += __shfl_xor(pt, 1);
            pt += __shfl_xor(pt, 2);
            if (c == 0) { sv[n2] = ps; tv[n2] = pt; }
        }
    }
}

// =============== kernel 3: edge-centric out = mean(sv[src]) + tv + c0 ===============
__global__ __launch_bounds__(256) void k_final(
    const int* __restrict__ bucketfill, const unsigned int* __restrict__ bucket,
    const int* __restrict__ deg, const float* __restrict__ sv, const float* __restrict__ tv,
    const float* __restrict__ uvc, float* __restrict__ out)
{
    __shared__ float lsum[NPB];
    int b = blockIdx.x;
    int tid = threadIdx.x;
    int cntb = bucketfill[b * BF_STRIDE];
    const unsigned int* bk = bucket + (size_t)b * CAP;

    if (tid < NPB) lsum[tid] = 0.f;
    __syncthreads();
    for (int i = tid; i < cntb; i += 256) {
        unsigned v = bk[i];
        int d = v & (NPB - 1);
        int s = (int)(v >> 7);
        atomicAdd(&lsum[d], sv[s]);
    }
    __syncthreads();
    if (tid < NPB) {
        int n = b * NPB + tid;
        if (n < NN) {
            float dg = (float)deg[n];
            out[n] = lsum[tid] / fmaxf(dg, 1.0f) + tv[n] + uvc[2 * HID_DIM];
        }
    }
}

extern "C" void kernel_launch(void* const* d_in, const int* in_sizes, int n_in,
                              void* d_out, int out_size, void* d_ws, size_t ws_size,
                              hipStream_t stream) {
    const float* x   = (const float*)d_in[0];
    const int*   ei  = (const int*)d_in[1];
    const float* Wl1 = (const float*)d_in[2];
    const float* bl1 = (const float*)d_in[3];
    const float* Wr1 = (const float*)d_in[4];
    const float* Wl2 = (const float*)d_in[5];
    const float* bl2 = (const float*)d_in[6];
    const float* Wr2 = (const float*)d_in[7];
    const float* Wfc = (const float*)d_in[8];
    const float* bfc = (const float*)d_in[9];
    float* out = (float*)d_out;

    const int* src = ei;
    const int* dst = ei + NE;

    // ws layout:
    int* bucketfill = (int*)d_ws;                        // NBK*BF_STRIDE = 12512 -> pad 12544
    int* deg        = bucketfill + 12544;                // NN
    float* uvc      = (float*)(deg + NN);                // 40
    float* sv       = uvc + 40;                          // NN
    float* tv       = sv + NN;                           // NN
    unsigned int* bucket = (unsigned int*)(tv + NN);     // NBK*CAP (10 MB)
    __half* zh      = (__half*)(bucket + (size_t)NBK * CAP);   // NN*16 halves (3.2 MB)
    float* rb       = (float*)(zh + (size_t)NN * HID_DIM);     // NN*16 floats

    hipMemsetAsync(bucketfill, 0, NBK * BF_STRIDE * sizeof(int), stream);

    k_phase1<<<GRID1, BS1, 0, stream>>>(x, src, dst, Wl1, bl1, Wr1,
                                        Wl2, bl2, Wr2, Wfc, bfc,
                                        bucketfill, bucket, zh, rb, uvc);
    k_sort_gather<<<NBK, 256, 0, stream>>>(bucketfill, bucket, zh, rb, uvc, deg, sv, tv);
    k_final<<<NBK, 256, 0, stream>>>(bucketfill, bucket, deg, sv, tv, uvc, out);
}